// Round 6
// baseline (2406.104 us; speedup 1.0000x reference)
//
#include <hip/hip_runtime.h>

// Problem constants
#define N_TH   4609      // D_THETA
#define A2W    4616      // A2p row width (dwords)
#define NJP    2305      // real j-pairs
#define NJPP   2312      // padded j-pairs (mult of 8; pad rows zero)
#define PRS    12        // Prow row stride (floats)
#define PRWN2  4624      // Prow rows (2*NJPP)
#define PCS    4612      // PcolX col stride (floats)
#define PW     4612      // part i-stride (floats)
#define TSTR   4612      // theta row stride (floats)
#define NB     32
#define NL     32
#define IND    10

// ws layout (float offsets); part sized by runtime KB; A2p follows part.
#define OF_DU    0          // 10,240
#define OF_PROW  10240      // 4624*12 = 55,488 -> end 65,728
#define OF_PCOL  65728      // 32*11*4612 = 1,623,424 -> end 1,689,152
#define OF_PART  1689152    // KB*11*4612
// A2p: 2312*4616 = 10,672,192 fl
// totals: KB=33 -> 56,142,000 B ; KB=17 -> 52,895,152 B (< proven-safe 55.03 MB)
#define NEED_KB33 56142000ULL

// ---------------------------------------------------------------------------
__global__ __launch_bounds__(256) void k_du(const float* __restrict__ xs,
                                            const float* __restrict__ ts,
                                            float* __restrict__ du) {
    int idx = blockIdx.x * 256 + threadIdx.x;
    if (idx >= NB * NL * IND) return;
    int d  = idx % IND;
    int bt = idx / IND;
    int t = bt % NL, b = bt / NL;
    if (t == 0) { du[idx] = 0.f; return; }
    float cur  = (d == 0) ? ts[b * NL + t]     : xs[(b * NL + t) * 9 + (d - 1)];
    float prev = (d == 0) ? ts[b * NL + t - 1] : xs[(b * NL + t - 1) * 9 + (d - 1)];
    du[idx] = cur - prev;
}

// ---------------------------------------------------------------------------
// P_0 = [theta0 | B] into Prow (4624 rows, stride 12, zero-padded) and PcolX
// kplane 0 cols 1..10.
__global__ __launch_bounds__(256) void k_p0(const float* __restrict__ th0,
                                            const float* __restrict__ Bm,
                                            float* __restrict__ Prow,
                                            float* __restrict__ PcolX) {
    int idx = blockIdx.x * 256 + threadIdx.x;   // over PRWN2*12
    if (idx >= PRWN2 * PRS) return;
    int i = idx / PRS, c = idx - i * PRS;
    float v = 0.f;
    if (i < N_TH) {
        if (c == 0) v = th0[i];
        else if (c <= 10) v = Bm[(size_t)i * 10 + (c - 1)];
    }
    Prow[idx] = v;
    if (c >= 1 && c <= 10 && i < PCS)
        PcolX[(size_t)c * PCS + i] = v;   // kplane 0, col c
}

// ---------------------------------------------------------------------------
// Transpose+convert+pack: A2p[jp*A2W + i] = bf16(A[i][2jp]-d) | bf16(A[i][2jp+1]-d)<<16
// Pad rows jp in [2305,2312) and cols i in [4609,4616) are zero.
__global__ __launch_bounds__(256) void k_tr(const float* __restrict__ A,
                                            unsigned int* __restrict__ A2p) {
    __shared__ float T[64][65];
    const int tid = threadIdx.x;
    const int i0 = blockIdx.x * 64;   // 0..72 (covers i < 4672 -> clip 4616)
    const int j0 = blockIdx.y * 64;   // 0..72 (covers jp < 2336 -> clip 2312)
#pragma unroll
    for (int e = 0; e < 16; e++) {
        int idx = e * 256 + tid;
        int r = idx >> 6, q = idx & 63;
        int i = i0 + r, j = j0 + q;
        float v = 0.f;
        if (i < N_TH && j < N_TH) {
            v = A[(size_t)i * N_TH + j];
            if (i == j) v -= 1.f;
        }
        T[r][q] = v;
    }
    __syncthreads();
#pragma unroll
    for (int e = 0; e < 8; e++) {
        int idx = e * 256 + tid;
        int jj2 = idx >> 6;           // 0..31 (jpair within tile)
        int ii  = idx & 63;
        int jp_g = (j0 >> 1) + jj2;
        int i = i0 + ii;
        if (jp_g < NJPP && i < A2W) {
            float v0 = T[ii][jj2 * 2];
            float v1 = T[ii][jj2 * 2 + 1];
            unsigned int u0 = __float_as_uint(v0);
            unsigned int u1 = __float_as_uint(v1);
            unsigned int r0 = (u0 + 0x7fffu + ((u0 >> 16) & 1u)) >> 16;  // RNE
            unsigned int r1 = (u1 + 0x7fffu + ((u1 >> 16) & 1u)) >> 16;
            A2p[(size_t)jp_g * A2W + i] = r0 | (r1 << 16);
        }
    }
}

// ---------------------------------------------------------------------------
// Step: part[bx][c][i] = sum_{jp in chunk} unpack2(A2p[jp][i]) . P[2jp..2jp+1][c]
// No LDS. P read with wave-uniform indices -> scalar loads (SGPR broadcast).
// A2p prefetched 8-deep into a statically-indexed register ring.
__global__ __launch_bounds__(256) void k_stepS(const unsigned int* __restrict__ A2p,
                                               const float* __restrict__ Prow,
                                               float* __restrict__ part,
                                               int jchunk) {
    const int tid = threadIdx.x;
    const int bx = blockIdx.x;
    const int jlo = bx * jchunk;
    int jn = NJPP - jlo; if (jn > jchunk) jn = jchunk;   // always mult of 8
    const int i = blockIdx.y * 256 + tid;
    const int iL = (i < A2W - 1) ? i : (A2W - 1);        // clamp loads

    float a00=0.f,a01=0.f,a02=0.f,a03=0.f,a04=0.f,a05=0.f,a06=0.f,a07=0.f,a08=0.f,a09=0.f,a10=0.f;

    const unsigned int* ap = A2p + (size_t)jlo * A2W + iL;
    const float4* pb4 = (const float4*)(Prow + (size_t)(2 * jlo) * PRS);

    unsigned int av[8];
#pragma unroll
    for (int u = 0; u < 8; u++) av[u] = ap[(size_t)u * A2W];

    for (int q = 0; q < jn; q += 8) {
        const bool pre = (q + 16 <= jn);
#pragma unroll
        for (int u = 0; u < 8; u++) {
            unsigned int a = av[u];
            if (pre) av[u] = ap[(size_t)(q + u + 8) * A2W];
            float f0 = __uint_as_float(a << 16);
            float f1 = __uint_as_float(a & 0xffff0000u);
            const float4 p0 = pb4[(q + u) * 6 + 0];
            const float4 p1 = pb4[(q + u) * 6 + 1];
            const float4 p2 = pb4[(q + u) * 6 + 2];
            const float4 p3 = pb4[(q + u) * 6 + 3];
            const float4 p4 = pb4[(q + u) * 6 + 4];
            const float4 p5 = pb4[(q + u) * 6 + 5];
            a00 = fmaf(f0, p0.x, a00);
            a01 = fmaf(f0, p0.y, a01);
            a02 = fmaf(f0, p0.z, a02);
            a03 = fmaf(f0, p0.w, a03);
            a04 = fmaf(f0, p1.x, a04);
            a05 = fmaf(f0, p1.y, a05);
            a06 = fmaf(f0, p1.z, a06);
            a07 = fmaf(f0, p1.w, a07);
            a08 = fmaf(f0, p2.x, a08);
            a09 = fmaf(f0, p2.y, a09);
            a10 = fmaf(f0, p2.z, a10);
            a00 = fmaf(f1, p3.x, a00);
            a01 = fmaf(f1, p3.y, a01);
            a02 = fmaf(f1, p3.z, a02);
            a03 = fmaf(f1, p3.w, a03);
            a04 = fmaf(f1, p4.x, a04);
            a05 = fmaf(f1, p4.y, a05);
            a06 = fmaf(f1, p4.z, a06);
            a07 = fmaf(f1, p4.w, a07);
            a08 = fmaf(f1, p5.x, a08);
            a09 = fmaf(f1, p5.y, a09);
            a10 = fmaf(f1, p5.z, a10);
        }
    }

    if (i < PW) {
        float* pp = part + (size_t)(bx * 11) * PW + i;
        pp[0]        = a00;
        pp[PW]       = a01;
        pp[2 * PW]   = a02;
        pp[3 * PW]   = a03;
        pp[4 * PW]   = a04;
        pp[5 * PW]   = a05;
        pp[6 * PW]   = a06;
        pp[7 * PW]   = a07;
        pp[8 * PW]   = a08;
        pp[9 * PW]   = a09;
        pp[10 * PW]  = a10;
    }
}

// ---------------------------------------------------------------------------
// P_k[i][c] = P_{k-1}[i][c] + sum_s part[s][c][i], float4 over i.
// Packed PcolX: c0 -> kplane k-1 col0 (bias for t=k-1); c1..10 -> kplane k (k<=31).
__global__ __launch_bounds__(256) void k_reduce(const float* __restrict__ part,
                                                float* __restrict__ Prow,
                                                float* __restrict__ PcolX,
                                                int k, int kb) {
    int t = blockIdx.x * 256 + threadIdx.x;   // over 11 * 1153
    if (t >= 11 * (PW / 4)) return;
    int c = t / (PW / 4), iq = t - c * (PW / 4);
    int i = iq * 4;
    const float4* p4 = (const float4*)part;
    float4 s;
    s.x = Prow[(size_t)(i + 0) * PRS + c];
    s.y = Prow[(size_t)(i + 1) * PRS + c];
    s.z = Prow[(size_t)(i + 2) * PRS + c];
    s.w = Prow[(size_t)(i + 3) * PRS + c];
    for (int sl = 0; sl < kb; sl++) {
        float4 v = p4[(size_t)(sl * 11 + c) * (PW / 4) + iq];
        s.x += v.x; s.y += v.y; s.z += v.z; s.w += v.w;
    }
    Prow[(size_t)(i + 0) * PRS + c] = s.x;
    Prow[(size_t)(i + 1) * PRS + c] = s.y;
    Prow[(size_t)(i + 2) * PRS + c] = s.z;
    Prow[(size_t)(i + 3) * PRS + c] = s.w;
    if (c == 0)
        *(float4*)(PcolX + ((size_t)(k - 1) * 11) * PCS + i) = s;
    else if (k <= 31)
        *(float4*)(PcolX + ((size_t)k * 11 + c) * PCS + i) = s;
}

// ---------------------------------------------------------------------------
// theta[bt][i] = bias + sum_{j<t,d} P_j[1+d][i] * du[b][t-j][d]
// GEMM M=1024, N=4609, K=320. Block 32 bt x 256 i; thread 4 bt x 8 i (2x float4).
// grid (19, 32).
__global__ __launch_bounds__(256) void k_conv(const float* __restrict__ du,
                                              const float* __restrict__ PcolX,
                                              float* __restrict__ theta) {
    __shared__ float CfT[32][36];    // [kk][m], m<32
    __shared__ float Pl[32][260];    // [kk][ii], ii<256
    const int tid = threadIdx.x;
    const int tn = tid & 31, tm = tid >> 5;   // tn: i-group, tm: bt-group
    const int i0  = blockIdx.x * 256;
    const int bt0 = blockIdx.y * 32;

    float acc[4][8];
#pragma unroll
    for (int r = 0; r < 4; r++)
#pragma unroll
        for (int n = 0; n < 8; n++) acc[r][n] = 0.f;

    for (int k0 = 0; k0 < 320; k0 += 32) {
#pragma unroll
        for (int s = 0; s < 4; s++) {
            int idx = s * 256 + tid;
            int m = idx >> 5, kk = idx & 31;
            int k = k0 + kk;
            int j = k / 10, d = k - j * 10;
            int bt = bt0 + m, t = bt & 31, b = bt >> 5;
            float v = 0.f;
            if (j < t) v = du[(size_t)(b * NL + (t - j)) * IND + d];
            CfT[kk][m] = v;
        }
#pragma unroll
        for (int kk = 0; kk < 32; kk++) {
            int k = k0 + kk;
            int j = k / 10, d = k - j * 10;
            int ig = i0 + tid;
            Pl[kk][tid] = (ig < N_TH) ? PcolX[((size_t)j * 11 + 1 + d) * PCS + ig] : 0.f;
        }
        __syncthreads();
#pragma unroll
        for (int kk = 0; kk < 32; kk++) {
            float4 a  = *(const float4*)&CfT[kk][tm * 4];
            float4 b0 = *(const float4*)&Pl[kk][tn * 4];
            float4 b1 = *(const float4*)&Pl[kk][128 + tn * 4];
            acc[0][0] = fmaf(a.x, b0.x, acc[0][0]);
            acc[0][1] = fmaf(a.x, b0.y, acc[0][1]);
            acc[0][2] = fmaf(a.x, b0.z, acc[0][2]);
            acc[0][3] = fmaf(a.x, b0.w, acc[0][3]);
            acc[0][4] = fmaf(a.x, b1.x, acc[0][4]);
            acc[0][5] = fmaf(a.x, b1.y, acc[0][5]);
            acc[0][6] = fmaf(a.x, b1.z, acc[0][6]);
            acc[0][7] = fmaf(a.x, b1.w, acc[0][7]);
            acc[1][0] = fmaf(a.y, b0.x, acc[1][0]);
            acc[1][1] = fmaf(a.y, b0.y, acc[1][1]);
            acc[1][2] = fmaf(a.y, b0.z, acc[1][2]);
            acc[1][3] = fmaf(a.y, b0.w, acc[1][3]);
            acc[1][4] = fmaf(a.y, b1.x, acc[1][4]);
            acc[1][5] = fmaf(a.y, b1.y, acc[1][5]);
            acc[1][6] = fmaf(a.y, b1.z, acc[1][6]);
            acc[1][7] = fmaf(a.y, b1.w, acc[1][7]);
            acc[2][0] = fmaf(a.z, b0.x, acc[2][0]);
            acc[2][1] = fmaf(a.z, b0.y, acc[2][1]);
            acc[2][2] = fmaf(a.z, b0.z, acc[2][2]);
            acc[2][3] = fmaf(a.z, b0.w, acc[2][3]);
            acc[2][4] = fmaf(a.z, b1.x, acc[2][4]);
            acc[2][5] = fmaf(a.z, b1.y, acc[2][5]);
            acc[2][6] = fmaf(a.z, b1.z, acc[2][6]);
            acc[2][7] = fmaf(a.z, b1.w, acc[2][7]);
            acc[3][0] = fmaf(a.w, b0.x, acc[3][0]);
            acc[3][1] = fmaf(a.w, b0.y, acc[3][1]);
            acc[3][2] = fmaf(a.w, b0.z, acc[3][2]);
            acc[3][3] = fmaf(a.w, b0.w, acc[3][3]);
            acc[3][4] = fmaf(a.w, b1.x, acc[3][4]);
            acc[3][5] = fmaf(a.w, b1.y, acc[3][5]);
            acc[3][6] = fmaf(a.w, b1.z, acc[3][6]);
            acc[3][7] = fmaf(a.w, b1.w, acc[3][7]);
        }
        __syncthreads();
    }

#pragma unroll
    for (int r = 0; r < 4; r++) {
        int bt = bt0 + tm * 4 + r;
        int t = bt & 31;
#pragma unroll
        for (int h = 0; h < 2; h++) {
            int i = i0 + h * 128 + tn * 4;
            float4 bb = *(const float4*)(PcolX + ((size_t)t * 11) * PCS + i);
            float4 o;
            o.x = acc[r][h * 4 + 0] + bb.x;
            o.y = acc[r][h * 4 + 1] + bb.y;
            o.z = acc[r][h * 4 + 2] + bb.z;
            o.w = acc[r][h * 4 + 3] + bb.w;
            float* dst = theta + (size_t)bt * TSTR + i;
            if (i + 3 < N_TH) {
                *(float4*)dst = o;
            } else {
                float ov[4] = {o.x, o.y, o.z, o.w};
#pragma unroll
                for (int e = 0; e < 4; e++)
                    if (i + e < N_TH) dst[e] = ov[e];
            }
        }
    }
}

// ---------------------------------------------------------------------------
__global__ __launch_bounds__(256) void k_mlp(const float* __restrict__ xs,
                                             const float* __restrict__ ts,
                                             const float* __restrict__ theta,
                                             float* __restrict__ out) {
    const int tid  = threadIdx.x;
    const int lane = tid & 63;
    const int half = (lane >> 5) & 1;
    const int o    = lane & 31;
    const int wv   = tid >> 6;
    const int bt   = blockIdx.x * 8 + wv * 2 + half;
    const int b = bt >> 5, t = bt & 31;
    const float* th = theta + (size_t)bt * TSTR;

    float u[10];
    u[0] = ts[b * NL + t];
#pragma unroll
    for (int d = 0; d < 9; d++) u[1 + d] = xs[(b * NL + t) * 9 + d];

    float acc = th[320 + o];
#pragma unroll
    for (int i = 0; i < 10; i++) acc = fmaf(th[o * 10 + i], u[i], acc);
    float h = fmaxf(acc, 0.f);

#pragma unroll
    for (int l = 0; l < 4; l++) {
        int base = 352 + l * 1056;
        float a2 = th[base + 1024 + o];
#pragma unroll
        for (int i = 0; i < 32; i++)
            a2 = fmaf(th[base + o * 32 + i], __shfl(h, i, 32), a2);
        h = fmaxf(a2, 0.f);
    }

    float contrib = th[4576 + o] * h;
#pragma unroll
    for (int m = 16; m >= 1; m >>= 1) contrib += __shfl_xor(contrib, m, 32);
    if (o == 0) out[bt] = contrib + th[4608];
}

// ---------------------------------------------------------------------------
extern "C" void kernel_launch(void* const* d_in, const int* in_sizes, int n_in,
                              void* d_out, int out_size, void* d_ws, size_t ws_size,
                              hipStream_t stream) {
    const float* xs  = (const float*)d_in[0];
    const float* ts  = (const float*)d_in[1];
    const float* A   = (const float*)d_in[2];
    const float* Bm  = (const float*)d_in[3];
    const float* th0 = (const float*)d_in[4];
    float* out = (float*)d_out;
    float* ws  = (float*)d_ws;

    const int KBv = (ws_size >= NEED_KB33) ? 33 : 17;
    const int jchunk = (KBv == 33) ? 72 : 136;   // mult of 8; KB*jchunk >= NJPP

    float* du    = ws + OF_DU;
    float* Prow  = ws + OF_PROW;
    float* PcolX = ws + OF_PCOL;
    float* part  = ws + OF_PART;
    unsigned int* A2p = (unsigned int*)(ws + OF_PART + (size_t)KBv * 11 * PW);
    float* theta = (float*)A2p;   // aliases A2p (dead after steps)

    k_du<<<40, 256, 0, stream>>>(xs, ts, du);
    k_p0<<<217, 256, 0, stream>>>(th0, Bm, Prow, PcolX);
    k_tr<<<dim3(73, 73), 256, 0, stream>>>(A, A2p);

    for (int k = 1; k <= 32; k++) {
        k_stepS<<<dim3(KBv, 19), 256, 0, stream>>>(A2p, Prow, part, jchunk);
        k_reduce<<<50, 256, 0, stream>>>(part, Prow, PcolX, k, KBv);
    }

    k_conv<<<dim3(19, 32), 256, 0, stream>>>(du, PcolX, theta);
    k_mlp<<<128, 256, 0, stream>>>(xs, ts, theta, out);
}

// Round 7
// 517.820 us; speedup vs baseline: 4.6466x; 4.6466x over previous
//
#include <hip/hip_runtime.h>

typedef __attribute__((ext_vector_type(8))) short bfrag8;   // 8 bf16 (4 VGPR)
typedef __attribute__((ext_vector_type(4))) float f32x4;    // MFMA acc

// Problem constants
#define N_TH   4609      // D_THETA
#define NIB    289       // i-blocks of 16 (289*16 = 4624)
#define NKC    148       // k-chunks of 32 (4*37; chunks >=145 are zero pad)
#define PRS    12        // Prow row stride (floats)
#define PCS    4612      // PcolX col stride (floats)
#define TSTR   4612      // theta row stride (floats)
#define NB     32
#define NL     32
#define IND    10

// ws layout (float offsets); total 12,714,560 fl = 50.86 MB (< proven 55.03 MB)
#define OF_DU    0          // 10,240
#define OF_PROW  10240      // 4624*12 = 55,488
#define OF_PMF   65728      // 2 bufs * 148*512 ushort = 75,776 fl
#define OF_PCOL  141504     // 32*11*4612 = 1,623,424
#define OF_A2M   1764928    // 289*148*256 = 10,949,632 fl ; theta aliases this

__device__ __forceinline__ unsigned short f2bf(float v) {
    unsigned int u = __float_as_uint(v);
    return (unsigned short)((u + 0x7fffu + ((u >> 16) & 1u)) >> 16);  // RNE
}

// ---------------------------------------------------------------------------
__global__ __launch_bounds__(256) void k_du(const float* __restrict__ xs,
                                            const float* __restrict__ ts,
                                            float* __restrict__ du) {
    int idx = blockIdx.x * 256 + threadIdx.x;
    if (idx >= NB * NL * IND) return;
    int d  = idx % IND;
    int bt = idx / IND;
    int t = bt % NL, b = bt / NL;
    if (t == 0) { du[idx] = 0.f; return; }
    float cur  = (d == 0) ? ts[b * NL + t]     : xs[(b * NL + t) * 9 + (d - 1)];
    float prev = (d == 0) ? ts[b * NL + t - 1] : xs[(b * NL + t - 1) * 9 + (d - 1)];
    du[idx] = cur - prev;
}

// ---------------------------------------------------------------------------
// P_0 into Prow (fp32), PcolX plane0 cols1..10, Pmf buf0 (bf16 B-frag layout),
// and zero Pmf buf1 (incl. all pad rows/cols of both).
__global__ __launch_bounds__(256) void k_p0(const float* __restrict__ th0,
                                            const float* __restrict__ Bm,
                                            float* __restrict__ Prow,
                                            float* __restrict__ PcolX,
                                            unsigned short* __restrict__ Pmf) {
    int idx = blockIdx.x * 256 + threadIdx.x;   // over 4736*16
    if (idx >= NKC * 32 * 16) return;
    int i = idx >> 4, c = idx & 15;
    float v = 0.f;
    if (i < N_TH && c < 11) {
        if (c == 0) v = th0[i];
        else v = Bm[(size_t)i * 10 + (c - 1)];
    }
    if (i < 4624 && c < 12) Prow[i * PRS + c] = v;
    if (c >= 1 && c <= 10 && i < PCS) PcolX[(size_t)c * PCS + i] = v;
    int kr = i & 31, chunk = i >> 5;
    size_t off = (size_t)chunk * 512 + (size_t)(((kr >> 3) * 16) + c) * 8 + (kr & 7);
    Pmf[off] = (v == 0.f) ? (unsigned short)0 : f2bf(v);
    Pmf[(size_t)NKC * 512 + off] = 0;
}

// ---------------------------------------------------------------------------
// Repack A -> A2m: MFMA A-frag layout. Chunk (ib,m) = 1KB: lane l=(g*16+r)
// holds bf16 A[ib*16+r][m*32+g*8+kk]-(i==j), kk=0..7 contiguous.
__global__ __launch_bounds__(256) void k_tr(const float* __restrict__ A,
                                            unsigned short* __restrict__ A2m) {
    __shared__ __align__(16) unsigned short Sm[8 * 512];
    const int tid = threadIdx.x;
    const int ib = blockIdx.x;        // 0..288
    const int mg = blockIdx.y;        // 0..18 (m = mg*8+ml, store if m<148)
    const int i0 = ib * 16, j0 = mg * 256;
    const int r = tid >> 4, q = tid & 15;
    const int i = i0 + r;

#pragma unroll
    for (int e = 0; e < 16; e++) {
        int jj = q * 16 + e;              // 0..255
        int j = j0 + jj;
        float x = 0.f;
        if (i < N_TH && j < N_TH) {
            x = A[(size_t)i * N_TH + j];
            if (i == j) x -= 1.f;
        }
        int ml = jj >> 5;
        int kr = jj & 31;
        Sm[ml * 512 + (((kr >> 3) * 16) + r) * 8 + (kr & 7)] =
            (x == 0.f) ? (unsigned short)0 : f2bf(x);
    }
    __syncthreads();

    // coalesced 32B/thread store of the 8KB block
    int ml_out = tid >> 5;
    if (mg * 8 + ml_out < NKC) {
        const uint4* s4 = (const uint4*)(Sm + tid * 16);
        uint4* dst = (uint4*)(A2m + ((size_t)ib * NKC + (size_t)mg * 8) * 512 + (size_t)tid * 16);
        dst[0] = s4[0];
        dst[1] = s4[1];
    }
}

// ---------------------------------------------------------------------------
// One scan step via MFMA: block ib owns 16 output rows; 4 waves split 148
// k-chunks (37 each); C = E*P_{k-1}; epilogue: P_k = P_{k-1}+C -> Prow fp32,
// PcolX planes, and bf16 B-frags into Pdst (double buffer).
__global__ __launch_bounds__(256) void k_stepM(const bfrag8* __restrict__ A2m,
                                               const bfrag8* __restrict__ Bsrc,
                                               unsigned short* __restrict__ Pdst,
                                               float* __restrict__ Prow,
                                               float* __restrict__ PcolX,
                                               int k) {
    __shared__ float red[4][256];
    const int tid  = threadIdx.x;
    const int lane = tid & 63;
    const int w    = tid >> 6;
    const int ib   = blockIdx.x;
    const int ms   = w * 37;

    const size_t abase = ((size_t)ib * NKC + ms) * 64 + lane;
    const size_t bbase = (size_t)ms * 64 + lane;

    bfrag8 a[4], b[4];
#pragma unroll
    for (int u = 0; u < 4; u++) {
        a[u] = A2m[abase + (size_t)u * 64];
        b[u] = Bsrc[bbase + (size_t)u * 64];
    }
    f32x4 acc = {0.f, 0.f, 0.f, 0.f};

#pragma unroll
    for (int g = 1; g <= 8; g++) {
        bfrag8 an[4], bn[4];
#pragma unroll
        for (int u = 0; u < 4; u++) {
            an[u] = A2m[abase + (size_t)(g * 4 + u) * 64];
            bn[u] = Bsrc[bbase + (size_t)(g * 4 + u) * 64];
        }
#pragma unroll
        for (int u = 0; u < 4; u++)
            acc = __builtin_amdgcn_mfma_f32_16x16x32_bf16(a[u], b[u], acc, 0, 0, 0);
#pragma unroll
        for (int u = 0; u < 4; u++) { a[u] = an[u]; b[u] = bn[u]; }
    }
#pragma unroll
    for (int u = 0; u < 4; u++)
        acc = __builtin_amdgcn_mfma_f32_16x16x32_bf16(a[u], b[u], acc, 0, 0, 0);
    {   // chunk ms+36
        bfrag8 at = A2m[abase + (size_t)36 * 64];
        bfrag8 bt = Bsrc[bbase + (size_t)36 * 64];
        acc = __builtin_amdgcn_mfma_f32_16x16x32_bf16(at, bt, acc, 0, 0, 0);
    }

    // C/D layout: col=lane&15, row=(lane>>4)*4+reg  [m89]
#pragma unroll
    for (int r = 0; r < 4; r++)
        red[w][(((lane >> 4) * 4) + r) * 16 + (lane & 15)] = acc[r];
    __syncthreads();

    {
        float s = red[0][tid] + red[1][tid] + red[2][tid] + red[3][tid];
        int row = tid >> 4, c = tid & 15;
        int i = ib * 16 + row;
        if (i < N_TH && c < 11) {
            float pnew = Prow[i * PRS + c] + s;
            Prow[i * PRS + c] = pnew;
            if (c == 0)
                PcolX[((size_t)(k - 1) * 11) * PCS + i] = pnew;
            else if (k <= 31)
                PcolX[((size_t)k * 11 + c) * PCS + i] = pnew;
            int kr = i & 31, chunk = i >> 5;
            Pdst[(size_t)chunk * 512 + (size_t)(((kr >> 3) * 16) + c) * 8 + (kr & 7)] = f2bf(pnew);
        }
    }
}

// ---------------------------------------------------------------------------
// theta[bt][i] = bias + sum_{j<t,d} P_j[1+d][i] * du[b][t-j][d]
// GEMM M=1024, N=4609, K=320. Block 32 bt x 256 i; thread 4 bt x 8 i.
__global__ __launch_bounds__(256) void k_conv(const float* __restrict__ du,
                                              const float* __restrict__ PcolX,
                                              float* __restrict__ theta) {
    __shared__ float CfT[32][36];
    __shared__ float Pl[32][260];
    const int tid = threadIdx.x;
    const int tn = tid & 31, tm = tid >> 5;
    const int i0  = blockIdx.x * 256;
    const int bt0 = blockIdx.y * 32;

    float acc[4][8];
#pragma unroll
    for (int r = 0; r < 4; r++)
#pragma unroll
        for (int n = 0; n < 8; n++) acc[r][n] = 0.f;

    for (int k0 = 0; k0 < 320; k0 += 32) {
#pragma unroll
        for (int s = 0; s < 4; s++) {
            int idx = s * 256 + tid;
            int m = idx >> 5, kk = idx & 31;
            int k = k0 + kk;
            int j = k / 10, d = k - j * 10;
            int bt = bt0 + m, t = bt & 31, b = bt >> 5;
            float v = 0.f;
            if (j < t) v = du[(size_t)(b * NL + (t - j)) * IND + d];
            CfT[kk][m] = v;
        }
#pragma unroll
        for (int kk = 0; kk < 32; kk++) {
            int k = k0 + kk;
            int j = k / 10, d = k - j * 10;
            int ig = i0 + tid;
            Pl[kk][tid] = (ig < N_TH) ? PcolX[((size_t)j * 11 + 1 + d) * PCS + ig] : 0.f;
        }
        __syncthreads();
#pragma unroll
        for (int kk = 0; kk < 32; kk++) {
            float4 a  = *(const float4*)&CfT[kk][tm * 4];
            float4 b0 = *(const float4*)&Pl[kk][tn * 4];
            float4 b1 = *(const float4*)&Pl[kk][128 + tn * 4];
            acc[0][0] = fmaf(a.x, b0.x, acc[0][0]);
            acc[0][1] = fmaf(a.x, b0.y, acc[0][1]);
            acc[0][2] = fmaf(a.x, b0.z, acc[0][2]);
            acc[0][3] = fmaf(a.x, b0.w, acc[0][3]);
            acc[0][4] = fmaf(a.x, b1.x, acc[0][4]);
            acc[0][5] = fmaf(a.x, b1.y, acc[0][5]);
            acc[0][6] = fmaf(a.x, b1.z, acc[0][6]);
            acc[0][7] = fmaf(a.x, b1.w, acc[0][7]);
            acc[1][0] = fmaf(a.y, b0.x, acc[1][0]);
            acc[1][1] = fmaf(a.y, b0.y, acc[1][1]);
            acc[1][2] = fmaf(a.y, b0.z, acc[1][2]);
            acc[1][3] = fmaf(a.y, b0.w, acc[1][3]);
            acc[1][4] = fmaf(a.y, b1.x, acc[1][4]);
            acc[1][5] = fmaf(a.y, b1.y, acc[1][5]);
            acc[1][6] = fmaf(a.y, b1.z, acc[1][6]);
            acc[1][7] = fmaf(a.y, b1.w, acc[1][7]);
            acc[2][0] = fmaf(a.z, b0.x, acc[2][0]);
            acc[2][1] = fmaf(a.z, b0.y, acc[2][1]);
            acc[2][2] = fmaf(a.z, b0.z, acc[2][2]);
            acc[2][3] = fmaf(a.z, b0.w, acc[2][3]);
            acc[2][4] = fmaf(a.z, b1.x, acc[2][4]);
            acc[2][5] = fmaf(a.z, b1.y, acc[2][5]);
            acc[2][6] = fmaf(a.z, b1.z, acc[2][6]);
            acc[2][7] = fmaf(a.z, b1.w, acc[2][7]);
            acc[3][0] = fmaf(a.w, b0.x, acc[3][0]);
            acc[3][1] = fmaf(a.w, b0.y, acc[3][1]);
            acc[3][2] = fmaf(a.w, b0.z, acc[3][2]);
            acc[3][3] = fmaf(a.w, b0.w, acc[3][3]);
            acc[3][4] = fmaf(a.w, b1.x, acc[3][4]);
            acc[3][5] = fmaf(a.w, b1.y, acc[3][5]);
            acc[3][6] = fmaf(a.w, b1.z, acc[3][6]);
            acc[3][7] = fmaf(a.w, b1.w, acc[3][7]);
        }
        __syncthreads();
    }

#pragma unroll
    for (int r = 0; r < 4; r++) {
        int bt = bt0 + tm * 4 + r;
        int t = bt & 31;
#pragma unroll
        for (int h = 0; h < 2; h++) {
            int i = i0 + h * 128 + tn * 4;
            float4 bb = *(const float4*)(PcolX + ((size_t)t * 11) * PCS + i);
            float4 o;
            o.x = acc[r][h * 4 + 0] + bb.x;
            o.y = acc[r][h * 4 + 1] + bb.y;
            o.z = acc[r][h * 4 + 2] + bb.z;
            o.w = acc[r][h * 4 + 3] + bb.w;
            float* dst = theta + (size_t)bt * TSTR + i;
            if (i + 3 < N_TH) {
                *(float4*)dst = o;
            } else {
                float ov[4] = {o.x, o.y, o.z, o.w};
#pragma unroll
                for (int e = 0; e < 4; e++)
                    if (i + e < N_TH) dst[e] = ov[e];
            }
        }
    }
}

// ---------------------------------------------------------------------------
__global__ __launch_bounds__(256) void k_mlp(const float* __restrict__ xs,
                                             const float* __restrict__ ts,
                                             const float* __restrict__ theta,
                                             float* __restrict__ out) {
    const int tid  = threadIdx.x;
    const int lane = tid & 63;
    const int half = (lane >> 5) & 1;
    const int o    = lane & 31;
    const int wv   = tid >> 6;
    const int bt   = blockIdx.x * 8 + wv * 2 + half;
    const int b = bt >> 5, t = bt & 31;
    const float* th = theta + (size_t)bt * TSTR;

    float u[10];
    u[0] = ts[b * NL + t];
#pragma unroll
    for (int d = 0; d < 9; d++) u[1 + d] = xs[(b * NL + t) * 9 + d];

    float acc = th[320 + o];
#pragma unroll
    for (int i = 0; i < 10; i++) acc = fmaf(th[o * 10 + i], u[i], acc);
    float h = fmaxf(acc, 0.f);

#pragma unroll
    for (int l = 0; l < 4; l++) {
        int base = 352 + l * 1056;
        float a2 = th[base + 1024 + o];
#pragma unroll
        for (int i = 0; i < 32; i++)
            a2 = fmaf(th[base + o * 32 + i], __shfl(h, i, 32), a2);
        h = fmaxf(a2, 0.f);
    }

    float contrib = th[4576 + o] * h;
#pragma unroll
    for (int m = 16; m >= 1; m >>= 1) contrib += __shfl_xor(contrib, m, 32);
    if (o == 0) out[bt] = contrib + th[4608];
}

// ---------------------------------------------------------------------------
extern "C" void kernel_launch(void* const* d_in, const int* in_sizes, int n_in,
                              void* d_out, int out_size, void* d_ws, size_t ws_size,
                              hipStream_t stream) {
    const float* xs  = (const float*)d_in[0];
    const float* ts  = (const float*)d_in[1];
    const float* A   = (const float*)d_in[2];
    const float* Bm  = (const float*)d_in[3];
    const float* th0 = (const float*)d_in[4];
    float* out = (float*)d_out;
    float* ws  = (float*)d_ws;

    float* du    = ws + OF_DU;
    float* Prow  = ws + OF_PROW;
    unsigned short* Pmf = (unsigned short*)(ws + OF_PMF);
    float* PcolX = ws + OF_PCOL;
    unsigned short* A2m = (unsigned short*)(ws + OF_A2M);
    float* theta = ws + OF_A2M;   // aliases A2m (dead after steps)

    k_du<<<40, 256, 0, stream>>>(xs, ts, du);
    k_p0<<<296, 256, 0, stream>>>(th0, Bm, Prow, PcolX, Pmf);
    k_tr<<<dim3(NIB, 19), 256, 0, stream>>>(A, A2m);

    for (int k = 1; k <= 32; k++) {
        const unsigned short* src = Pmf + (size_t)((k - 1) & 1) * (NKC * 512);
        unsigned short* dst       = Pmf + (size_t)(k & 1) * (NKC * 512);
        k_stepM<<<NIB, 256, 0, stream>>>((const bfrag8*)A2m, (const bfrag8*)src,
                                         dst, Prow, PcolX, k);
    }

    k_conv<<<dim3(19, 32), 256, 0, stream>>>(du, PcolX, theta);
    k_mlp<<<128, 256, 0, stream>>>(xs, ts, theta, out);
}